// Round 7
// baseline (369.988 us; speedup 1.0000x reference)
//
#include <hip/hip_runtime.h>
#include <math.h>

#define S4_H   128
#define S4_T   12
#define S4_S2  32
#define S4_NL  2
#define S4_N   1024
#define S4_BN  (16 * 1024)

typedef float f4 __attribute__((ext_vector_type(4)));
typedef short s8v __attribute__((ext_vector_type(8)));   // 8 bf16 bit-patterns

// per-wave LDS slice: union of gT (ushort[16][144] = 4608 B) and
// hb (float[128][17] = 8704 B). 17-dword row stride => conflict-free h reads.
#define LDS_PER_WAVE 8704

// wave-local LDS fence: all this wave's outstanding LDS ops retired.
// sched_barrier stops hipcc hoisting reg-only ops across the asm (rule #18).
#define LGKM_FENCE()                                        \
  do {                                                      \
    asm volatile("s_waitcnt lgkmcnt(0)" ::: "memory");      \
    __builtin_amdgcn_sched_barrier(0);                      \
  } while (0)

__device__ __forceinline__ unsigned short f2bf(float f) {
  unsigned int u = __builtin_bit_cast(unsigned int, f);
  u += 0x7fffu + ((u >> 16) & 1u);   // RNE
  return (unsigned short)(u >> 16);
}

// gelu(x) ~= x * sigmoid(1.5957691x(1 + 0.044715x^2))  (tanh form)
__device__ __forceinline__ float fast_gelu(float x) {
  const float u = 1.5957691216057308f * x * fmaf(0.044715f, x * x, 1.0f);
  return x * __builtin_amdgcn_rcpf(1.0f + __expf(-u));
}
__device__ __forceinline__ float fast_sigmoid(float g) {
  return __builtin_amdgcn_rcpf(1.0f + __expf(-g));
}

// ---------------------------------------------------------------------------
// S4D kernel row: k[h][t] = 2*Re( sum_n C_n * exp(dtA_n)^t ), ZOH discretized.
// ---------------------------------------------------------------------------
__device__ __forceinline__ void s4d_row(const float* __restrict__ log_A_real,
                                        const float* __restrict__ A_imag,
                                        const float* __restrict__ C_re,
                                        const float* __restrict__ C_im,
                                        const float* __restrict__ log_dt,
                                        int lh, float* kk) {
  const float dt = expf(log_dt[lh]);
#pragma unroll
  for (int t = 0; t < S4_T; ++t) kk[t] = 0.f;
  const int base = lh * S4_S2;
  for (int n = 0; n < S4_S2; ++n) {
    const float ar = -expf(log_A_real[base + n]);
    const float ai = A_imag[base + n];
    const float m  = expf(ar * dt);
    const float di = ai * dt;
    float sdi, cdi;
    sincosf(di, &sdi, &cdi);
    const float er = m * cdi, ei = m * sdi;           // exp(dt*A)
    const float inv = 1.0f / (ar * ar + ai * ai);
    const float x0 = er - 1.0f;
    const float qr = (x0 * ar + ei * ai) * inv;       // (exp(dtA)-1)/A
    const float qi = (ei * ar - x0 * ai) * inv;
    const float c0r = C_re[base + n], c0i = C_im[base + n];
    const float cr = c0r * qr - c0i * qi;             // C_tilde
    const float ci = c0r * qi + c0i * qr;
    float vr = 1.f, vi = 0.f;                         // V = exp(dtA)^t
#pragma unroll
    for (int t = 0; t < S4_T; ++t) {
      kk[t] = fmaf(cr, vr, fmaf(-ci, vi, kk[t]));
      const float nvr = vr * er - vi * ei;
      vi = vr * ei + vi * er;
      vr = nvr;
    }
  }
#pragma unroll
  for (int t = 0; t < S4_T; ++t) kk[t] *= 2.0f;
}

// prep: W fp32 -> bf16 bits in ws, and S4D kernel k into ws.
__global__ __launch_bounds__(256) void s4_prep(
    const float* __restrict__ oW, const float* __restrict__ lAr,
    const float* __restrict__ Aim, const float* __restrict__ Cre,
    const float* __restrict__ Cim, const float* __restrict__ ldt,
    unsigned short* __restrict__ Wbf, float* __restrict__ kout) {
  const int tid = blockIdx.x * 256 + (int)threadIdx.x;
  const int i = tid * 4;
  if (i < S4_NL * 2 * S4_H * S4_H) {
    const f4 v = *reinterpret_cast<const f4*>(&oW[i]);
    ushort4 o;
    o.x = f2bf(v[0]); o.y = f2bf(v[1]); o.z = f2bf(v[2]); o.w = f2bf(v[3]);
    *reinterpret_cast<ushort4*>(&Wbf[i]) = o;
  }
  if (tid < S4_NL * S4_H) {
    float kk[S4_T];
    s4d_row(lAr, Aim, Cre, Cim, ldt, tid, kk);
#pragma unroll
    for (int t = 0; t < S4_T; ++t) kout[tid * S4_T + t] = kk[t];
  }
}

// ---------------------------------------------------------------------------
// Wave-autonomous S4: one wave = one sequence, ZERO block barriers.
// Residual stream lives in registers in MFMA C-layout (hC[8] f4:
// rows 16i+4q+j, col t=lane&15). LDS (per-wave slice) used only for the
// h-major <-> C-layout transposes; ordering via wave-local lgkmcnt fences.
// ---------------------------------------------------------------------------
__global__ __launch_bounds__(256, 4) void s4_wave(
    const float* __restrict__ x, const float* __restrict__ enc_W,
    const float* __restrict__ enc_b, const float* __restrict__ Dp,
    const float* __restrict__ out_b, const float* __restrict__ ln_g,
    const float* __restrict__ ln_b, const float* __restrict__ sc_W,
    const float* __restrict__ sc_b, const unsigned short* __restrict__ Wbf,
    const float* __restrict__ kws, float* __restrict__ out) {
  __shared__ __align__(16) char lds_raw[4 * LDS_PER_WAVE];

  const int tid  = threadIdx.x;
  const int w    = tid >> 6;
  const int lane = tid & 63;
  const int q    = lane >> 4;        // k-group / D-row group
  const int t    = lane & 15;        // A-row (GEMM) and D-column (= timestep)
  const int seq  = blockIdx.x * 4 + w;

  char* Lp = &lds_raw[w * LDS_PER_WAVE];
  unsigned short* gT = (unsigned short*)Lp;  // gT[tt*144 + h]  (bf16)
  float* hbp = (float*)Lp;                   // hbp[h*17 + tt]  (fp32)

  // x row (48 B) in registers; xC = x[t] for the C-layout encoder.
  const float* xp = x + (size_t)seq * S4_T;
  const f4 xq0 = *(const f4*)xp, xq1 = *(const f4*)(xp + 4),
           xq2 = *(const f4*)(xp + 8);
  const float xv[S4_T] = {xq0[0], xq0[1], xq0[2], xq0[3], xq1[0], xq1[1],
                          xq1[2], xq1[3], xq2[0], xq2[1], xq2[2], xq2[3]};
  const float xC = xp[t < S4_T ? t : S4_T - 1];  // cols >=12 are discarded

  // residual in C layout: hC[i][j] = encoder output at row 16i+4q+j, col t
  f4 hC[8];
#pragma unroll
  for (int i = 0; i < 8; ++i) {
    const int ro = 16 * i + 4 * q;
    const f4 ew = *(const f4*)&enc_W[ro];
    const f4 eb = *(const f4*)&enc_b[ro];
#pragma unroll
    for (int j = 0; j < 4; ++j) hC[i][j] = fmaf(xC, ew[j], eb[j]);
  }

  for (int l = 0; l < S4_NL; ++l) {
    // ---- conv inputs z for owned channels h = lane, lane+64 (h-major) ----
    float z[2][S4_T];
    if (l == 0) {
#pragma unroll
      for (int hh = 0; hh < 2; ++hh) {
        const int h = lane + 64 * hh;
        const float ew = enc_W[h], eb = enc_b[h];
#pragma unroll
        for (int tt = 0; tt < S4_T; ++tt) z[hh][tt] = fmaf(xv[tt], ew, eb);
      }
    } else {
#pragma unroll
      for (int hh = 0; hh < 2; ++hh) {
        const int h = lane + 64 * hh;
#pragma unroll
        for (int tt = 0; tt < S4_T; ++tt) z[hh][tt] = hbp[h * 17 + tt];
      }
      LGKM_FENCE();  // hb reads retired before gT overwrites the union
    }
    // ---- causal conv + D*z + GELU -> gT (bf16, t-major) ----
#pragma unroll
    for (int hh = 0; hh < 2; ++hh) {
      const int h = lane + 64 * hh;
      const float* kp = kws + (size_t)(l * S4_H + h) * S4_T;
      const f4 k0 = *(const f4*)kp, k1 = *(const f4*)(kp + 4),
               k2 = *(const f4*)(kp + 8);
      const float kr[S4_T] = {k0[0], k0[1], k0[2], k0[3], k1[0], k1[1],
                              k1[2], k1[3], k2[0], k2[1], k2[2], k2[3]};
      const float dl = Dp[l * S4_H + h];
#pragma unroll
      for (int tt = 0; tt < S4_T; ++tt) {
        float a = dl * z[hh][tt];
#pragma unroll
        for (int ss = 0; ss <= tt; ++ss) a = fmaf(kr[tt - ss], z[hh][ss], a);
        gT[tt * 144 + h] = f2bf(fast_gelu(a));
      }
    }
    LGKM_FENCE();  // all lanes' gT writes visible to the wave

    // ---- B fragments: col = t, k = q*8 + j + 32*ks (proven R2 k-map) ----
    s8v bfv[4];
#pragma unroll
    for (int ks = 0; ks < 4; ++ks)
      bfv[ks] = *(const s8v*)(gT + t * 144 + q * 8 + 32 * ks);

    // ---- 16 M-tiles (8 val/gate pairs), full K per tile, GLU+residual ----
    const unsigned short* WL = Wbf + (size_t)l * 2 * S4_H * S4_H;
#pragma unroll
    for (int i = 0; i < 8; ++i) {
      const unsigned short* wpV = WL + (size_t)(16 * i + t) * S4_H + q * 8;
      const unsigned short* wpG = wpV + (size_t)S4_H * S4_H;
      f4 aV = {0.f, 0.f, 0.f, 0.f}, aG = {0.f, 0.f, 0.f, 0.f};
#pragma unroll
      for (int ks = 0; ks < 4; ++ks) {
        const s8v afV = *(const s8v*)(wpV + 32 * ks);
        const s8v afG = *(const s8v*)(wpG + 32 * ks);
        aV = __builtin_amdgcn_mfma_f32_16x16x32_bf16(afV, bfv[ks], aV, 0, 0, 0);
        aG = __builtin_amdgcn_mfma_f32_16x16x32_bf16(afG, bfv[ks], aG, 0, 0, 0);
      }
      const int ro = 16 * i + 4 * q;
      const f4 obV = *(const f4*)&out_b[l * 2 * S4_H + ro];
      const f4 obG = *(const f4*)&out_b[l * 2 * S4_H + S4_H + ro];
#pragma unroll
      for (int j = 0; j < 4; ++j) {
        const float vv = aV[j] + obV[j];
        const float gg = aG[j] + obG[j];
        hC[i][j] += vv * fast_sigmoid(gg);   // residual add, in-register
      }
    }

    // ---- LayerNorm over h per column t: 32 regs + 2 shuffles ----
    float s1 = 0.f, s2 = 0.f;
#pragma unroll
    for (int i = 0; i < 8; ++i)
#pragma unroll
      for (int j = 0; j < 4; ++j) {
        s1 += hC[i][j];
        s2 = fmaf(hC[i][j], hC[i][j], s2);
      }
    s1 += __shfl_xor(s1, 16); s1 += __shfl_xor(s1, 32);
    s2 += __shfl_xor(s2, 16); s2 += __shfl_xor(s2, 32);
    const float mu   = s1 * (1.0f / S4_H);
    const float var  = s2 * (1.0f / S4_H) - mu * mu;
    const float rstd = rsqrtf(var + 1e-5f);
#pragma unroll
    for (int i = 0; i < 8; ++i) {
      const int ro = 16 * i + 4 * q;
      const f4 lgv = *(const f4*)&ln_g[l * S4_H + ro];
      const f4 lbv = *(const f4*)&ln_b[l * S4_H + ro];
#pragma unroll
      for (int j = 0; j < 4; ++j) {
        hC[i][j] = fmaf((hC[i][j] - mu) * rstd, lgv[j], lbv[j]);
        hbp[(ro + j) * 17 + t] = hC[i][j];   // transpose out for next conv
      }
    }
    LGKM_FENCE();  // hb visible before next conv / output reads
  }

  // ---- output (B,H,N,T) + 1x1 conv shortcut (48 B contiguous per lane) ----
  const int b = seq >> 10, n = seq & (S4_N - 1);
#pragma unroll
  for (int hh = 0; hh < 2; ++hh) {
    const int h = lane + 64 * hh;
    const float sw = sc_W[h], sb = sc_b[h];
    float ov[S4_T];
#pragma unroll
    for (int tt = 0; tt < S4_T; ++tt)
      ov[tt] = hbp[h * 17 + tt] + fmaf(sw, xv[tt], sb);
    float* op = out + (size_t)((b * S4_H + h) * S4_N + n) * S4_T;
    const f4 o0 = {ov[0], ov[1], ov[2], ov[3]};
    const f4 o1 = {ov[4], ov[5], ov[6], ov[7]};
    const f4 o2 = {ov[8], ov[9], ov[10], ov[11]};
    *(f4*)(op)     = o0;
    *(f4*)(op + 4) = o1;
    *(f4*)(op + 8) = o2;
  }
}

// ---------------------------------------------------------------------------
// Fallback (no workspace): round-1 fp32 kernel, inline-k variant (exact math).
// ---------------------------------------------------------------------------
#define S4F_SEQ 4
__global__ __launch_bounds__(256) void s4_main_f32(
    const float* __restrict__ x, const float* __restrict__ enc_W,
    const float* __restrict__ enc_b, const float* __restrict__ log_A_real,
    const float* __restrict__ A_imag, const float* __restrict__ C_re,
    const float* __restrict__ C_im, const float* __restrict__ log_dt,
    const float* __restrict__ Dp, const float* __restrict__ out_W,
    const float* __restrict__ out_b, const float* __restrict__ ln_g,
    const float* __restrict__ ln_b, const float* __restrict__ sc_W,
    const float* __restrict__ sc_b, float* __restrict__ out) {
  __shared__ __align__(16) float hbuf[S4F_SEQ][S4_H][S4_T];
  __shared__ __align__(16) float gbuf[S4F_SEQ][S4_H][S4_T];
  __shared__ __align__(16) float kbuf[S4_NL][S4_H][S4_T];
  __shared__ __align__(16) float xbuf[S4F_SEQ][S4_T];
  const int tid = threadIdx.x;
  const int seq0 = blockIdx.x * S4F_SEQ;
  if (tid < S4F_SEQ * S4_T) {
    const int s = tid / S4_T, t = tid - s * S4_T;
    xbuf[s][t] = x[(seq0 + s) * S4_T + t];
  }
  {
    float kk[S4_T];
    s4d_row(log_A_real, A_imag, C_re, C_im, log_dt, tid, kk);
#pragma unroll
    for (int t = 0; t < S4_T; ++t) (&kbuf[0][0][0])[tid * S4_T + t] = kk[t];
  }
  __syncthreads();
  for (int r = tid; r < S4F_SEQ * S4_H; r += 256) {
    const int s = r >> 7, h = r & (S4_H - 1);
    const float ew = enc_W[h], eb = enc_b[h];
#pragma unroll
    for (int t = 0; t < S4_T; ++t) hbuf[s][h][t] = fmaf(xbuf[s][t], ew, eb);
  }
  for (int l = 0; l < S4_NL; ++l) {
    __syncthreads();
    for (int r = tid; r < S4F_SEQ * S4_H; r += 256) {
      const int s = r >> 7, h = r & (S4_H - 1);
      float z[S4_T], kr[S4_T];
#pragma unroll
      for (int t = 0; t < S4_T; ++t) {
        z[t] = hbuf[s][h][t];
        kr[t] = kbuf[l][h][t];
      }
      const float dl = Dp[l * S4_H + h];
#pragma unroll
      for (int t = 0; t < S4_T; ++t) {
        float a = dl * z[t];
#pragma unroll
        for (int ss = 0; ss <= t; ++ss) a = fmaf(kr[t - ss], z[ss], a);
        gbuf[s][h][t] = 0.5f * a * (1.0f + erff(a * 0.70710678118654752f));
      }
    }
    __syncthreads();
    {
      const int op = tid & (S4_H - 1);
      const int sg = tid >> 7;
      const float* __restrict__ W0 = out_W + (size_t)(l * 2 * S4_H + op) * S4_H;
      const float* __restrict__ W1 = W0 + S4_H * S4_H;
      float acc0[2][S4_T], acc1[2][S4_T];
#pragma unroll
      for (int s2 = 0; s2 < 2; ++s2)
#pragma unroll
        for (int t = 0; t < S4_T; ++t) { acc0[s2][t] = 0.f; acc1[s2][t] = 0.f; }
      for (int h0 = 0; h0 < S4_H; h0 += 4) {
        const float4 w0 = *reinterpret_cast<const float4*>(W0 + h0);
        const float4 w1 = *reinterpret_cast<const float4*>(W1 + h0);
        const float w0a[4] = {w0.x, w0.y, w0.z, w0.w};
        const float w1a[4] = {w1.x, w1.y, w1.z, w1.w};
#pragma unroll
        for (int j = 0; j < 4; ++j) {
#pragma unroll
          for (int s2 = 0; s2 < 2; ++s2) {
            const float* gp = &gbuf[2 * sg + s2][h0 + j][0];
            const float4 ga = *reinterpret_cast<const float4*>(gp);
            const float4 gc = *reinterpret_cast<const float4*>(gp + 4);
            const float4 ge = *reinterpret_cast<const float4*>(gp + 8);
            const float gg[S4_T] = {ga.x, ga.y, ga.z, ga.w, gc.x, gc.y,
                                    gc.z, gc.w, ge.x, ge.y, ge.z, ge.w};
#pragma unroll
            for (int t = 0; t < S4_T; ++t) {
              acc0[s2][t] = fmaf(w0a[j], gg[t], acc0[s2][t]);
              acc1[s2][t] = fmaf(w1a[j], gg[t], acc1[s2][t]);
            }
          }
        }
      }
      const float b0 = out_b[l * 2 * S4_H + op];
      const float b1 = out_b[l * 2 * S4_H + S4_H + op];
#pragma unroll
      for (int s2 = 0; s2 < 2; ++s2) {
        const int seq = 2 * sg + s2;
#pragma unroll
        for (int t = 0; t < S4_T; ++t) {
          const float a = acc0[s2][t] + b0;
          const float g = acc1[s2][t] + b1;
          hbuf[seq][op][t] += a * (1.0f / (1.0f + expf(-g)));
        }
      }
    }
    __syncthreads();
    {
      const int col = tid >> 2;
      const int ing = tid & 3;
      if (col < S4F_SEQ * S4_T) {
        const int s = col / S4_T, t = col - s * S4_T;
        float s1 = 0.f, s2v = 0.f;
#pragma unroll
        for (int i = 0; i < S4_H / 4; ++i) {
          const float v = hbuf[s][ing * 32 + i][t];
          s1 += v;
          s2v = fmaf(v, v, s2v);
        }
        s1 += __shfl_xor(s1, 1, 4); s1 += __shfl_xor(s1, 2, 4);
        s2v += __shfl_xor(s2v, 1, 4); s2v += __shfl_xor(s2v, 2, 4);
        const float mu = s1 * (1.0f / S4_H);
        const float var = s2v * (1.0f / S4_H) - mu * mu;
        const float rstd = rsqrtf(var + 1e-5f);
#pragma unroll
        for (int i = 0; i < S4_H / 4; ++i) {
          const int h = ing * 32 + i;
          const float v = hbuf[s][h][t];
          hbuf[s][h][t] =
              fmaf((v - mu) * rstd, ln_g[l * S4_H + h], ln_b[l * S4_H + h]);
        }
      }
    }
  }
  __syncthreads();
  for (int r = tid; r < S4F_SEQ * S4_H; r += 256) {
    const int s = r >> 7, h = r & (S4_H - 1);
    const int bn = seq0 + s;
    const int b = bn >> 10, n = bn & (S4_N - 1);
    const float sw = sc_W[h], sb = sc_b[h];
#pragma unroll
    for (int q = 0; q < 3; ++q) {
      float4 o;
      const float4 hv0 = *reinterpret_cast<const float4*>(&hbuf[s][h][4 * q]);
      const float4 xv = *reinterpret_cast<const float4*>(&xbuf[s][4 * q]);
      o.x = hv0.x + fmaf(sw, xv.x, sb);
      o.y = hv0.y + fmaf(sw, xv.y, sb);
      o.z = hv0.z + fmaf(sw, xv.z, sb);
      o.w = hv0.w + fmaf(sw, xv.w, sb);
      reinterpret_cast<float4*>(out + (size_t)((b * S4_H + h) * S4_N + n) *
                                          S4_T)[q] = o;
    }
  }
}

extern "C" void kernel_launch(void* const* d_in, const int* in_sizes, int n_in,
                              void* d_out, int out_size, void* d_ws,
                              size_t ws_size, hipStream_t stream) {
  const float* x     = (const float*)d_in[0];
  const float* enc_W = (const float*)d_in[1];
  const float* enc_b = (const float*)d_in[2];
  const float* lAr   = (const float*)d_in[3];
  const float* Aim   = (const float*)d_in[4];
  const float* Cre   = (const float*)d_in[5];
  const float* Cim   = (const float*)d_in[6];
  const float* ldt   = (const float*)d_in[7];
  const float* Dp    = (const float*)d_in[8];
  const float* oW    = (const float*)d_in[9];
  const float* ob    = (const float*)d_in[10];
  const float* lg    = (const float*)d_in[11];
  const float* lb    = (const float*)d_in[12];
  const float* scW   = (const float*)d_in[13];
  const float* scb   = (const float*)d_in[14];
  float* out = (float*)d_out;

  const size_t wbytes = (size_t)(S4_NL * 2 * S4_H * S4_H) * sizeof(unsigned short); // 131072
  const size_t kbytes = (size_t)(S4_NL * S4_H * S4_T) * sizeof(float);              // 12288
  if (ws_size >= wbytes + kbytes) {
    unsigned short* Wbf = (unsigned short*)d_ws;
    float* kws = (float*)((char*)d_ws + wbytes);
    s4_prep<<<64, 256, 0, stream>>>(oW, lAr, Aim, Cre, Cim, ldt, Wbf, kws);
    s4_wave<<<S4_BN / 4, 256, 0, stream>>>(x, enc_W, enc_b, Dp, ob, lg, lb,
                                           scW, scb, Wbf, kws, out);
  } else {
    s4_main_f32<<<S4_BN / S4F_SEQ, 256, 0, stream>>>(
        x, enc_W, enc_b, lAr, Aim, Cre, Cim, ldt, Dp, oW, ob, lg, lb, scW,
        scb, out);
  }
}

// Round 8
// 158.271 us; speedup vs baseline: 2.3377x; 2.3377x over previous
//
#include <hip/hip_runtime.h>
#include <math.h>

#define S4_H   128
#define S4_HP  136          // padded leading dim (dword stride 136 ≡ 8 mod 32)
#define S4_T   12
#define S4_TT  48           // 4 seqs * 12 timesteps per pipeline
#define S4_S2  32
#define S4_SEQ 4            // sequences per pipeline
#define S4_PB  2            // pipelines per block (A/B interleave)
#define S4_NL  2
#define S4_N   1024
#define S4_BN  (16 * 1024)

typedef float f4 __attribute__((ext_vector_type(4)));
typedef short s8v __attribute__((ext_vector_type(8)));   // 8 bf16 bit-patterns

__device__ __forceinline__ unsigned short f2bf(float f) {
  unsigned int u = __builtin_bit_cast(unsigned int, f);
  u += 0x7fffu + ((u >> 16) & 1u);   // RNE
  return (unsigned short)(u >> 16);
}

// gelu(x) ~= x * sigmoid(1.5957691x(1 + 0.044715x^2))  (tanh form)
__device__ __forceinline__ float fast_gelu(float x) {
  const float u = 1.5957691216057308f * x * fmaf(0.044715f, x * x, 1.0f);
  return x * __builtin_amdgcn_rcpf(1.0f + __expf(-u));
}
__device__ __forceinline__ float fast_sigmoid(float g) {
  return __builtin_amdgcn_rcpf(1.0f + __expf(-g));
}

// ---------------------------------------------------------------------------
// S4D kernel row: k[h][t] = 2*Re( sum_n C_n * exp(dtA_n)^t ), ZOH discretized.
// ---------------------------------------------------------------------------
__device__ __forceinline__ void s4d_row(const float* __restrict__ log_A_real,
                                        const float* __restrict__ A_imag,
                                        const float* __restrict__ C_re,
                                        const float* __restrict__ C_im,
                                        const float* __restrict__ log_dt,
                                        int lh, float* kk) {
  const float dt = expf(log_dt[lh]);
#pragma unroll
  for (int t = 0; t < S4_T; ++t) kk[t] = 0.f;
  const int base = lh * S4_S2;
  for (int n = 0; n < S4_S2; ++n) {
    const float ar = -expf(log_A_real[base + n]);
    const float ai = A_imag[base + n];
    const float m  = expf(ar * dt);
    const float di = ai * dt;
    float sdi, cdi;
    sincosf(di, &sdi, &cdi);
    const float er = m * cdi, ei = m * sdi;           // exp(dt*A)
    const float inv = 1.0f / (ar * ar + ai * ai);
    const float x0 = er - 1.0f;
    const float qr = (x0 * ar + ei * ai) * inv;       // (exp(dtA)-1)/A
    const float qi = (ei * ar - x0 * ai) * inv;
    const float c0r = C_re[base + n], c0i = C_im[base + n];
    const float cr = c0r * qr - c0i * qi;             // C_tilde
    const float ci = c0r * qi + c0i * qr;
    float vr = 1.f, vi = 0.f;                         // V = exp(dtA)^t
#pragma unroll
    for (int t = 0; t < S4_T; ++t) {
      kk[t] = fmaf(cr, vr, fmaf(-ci, vi, kk[t]));
      const float nvr = vr * er - vi * ei;
      vi = vr * ei + vi * er;
      vr = nvr;
    }
  }
#pragma unroll
  for (int t = 0; t < S4_T; ++t) kk[t] *= 2.0f;
}

// prep: W fp32 -> bf16 bits in ws, and S4D kernel k into ws.
__global__ __launch_bounds__(256) void s4_prep(
    const float* __restrict__ oW, const float* __restrict__ lAr,
    const float* __restrict__ Aim, const float* __restrict__ Cre,
    const float* __restrict__ Cim, const float* __restrict__ ldt,
    unsigned short* __restrict__ Wbf, float* __restrict__ kout) {
  const int tid = blockIdx.x * 256 + (int)threadIdx.x;
  const int i = tid * 4;
  if (i < S4_NL * 2 * S4_H * S4_H) {
    const f4 v = *reinterpret_cast<const f4*>(&oW[i]);
    ushort4 o;
    o.x = f2bf(v[0]); o.y = f2bf(v[1]); o.z = f2bf(v[2]); o.w = f2bf(v[3]);
    *reinterpret_cast<ushort4*>(&Wbf[i]) = o;
  }
  if (tid < S4_NL * S4_H) {
    float kk[S4_T];
    s4d_row(lAr, Aim, Cre, Cim, ldt, tid, kk);
#pragma unroll
    for (int t = 0; t < S4_T; ++t) kout[tid * S4_T + t] = kk[t];
  }
}

// ---------------------------------------------------------------------------
// Fused S4 block, MFMA channel mix, TWO independent pipelines per block
// (A = seqs 0-3, B = seqs 4-7). Per-sequence numerics identical to the
// proven R3 kernel; each barrier region holds 2x independent work (ILP).
// ---------------------------------------------------------------------------
__global__ __launch_bounds__(256, 3) void s4_mfma2(
    const float* __restrict__ x, const float* __restrict__ enc_W,
    const float* __restrict__ enc_b, const float* __restrict__ Dp,
    const float* __restrict__ out_b, const float* __restrict__ ln_g,
    const float* __restrict__ ln_b, const float* __restrict__ sc_W,
    const float* __restrict__ sc_b, const unsigned short* __restrict__ Wbf,
    const float* __restrict__ kws, float* __restrict__ out) {
  __shared__ __align__(16) float hb[S4_PB][S4_TT][S4_HP];          // 52224 B
  __shared__ __align__(16) unsigned short gb[S4_PB][S4_TT][S4_HP]; // 26112 B
  __shared__ __align__(16) float xb[S4_PB][S4_SEQ][S4_T];          // 384 B

  const int tid  = threadIdx.x;
  const int seq0 = blockIdx.x * (S4_PB * S4_SEQ);
  const int hch  = tid & (S4_H - 1);

  // stage x for both pipelines (96 values)
  if (tid < S4_PB * S4_SEQ * S4_T) {
    const int pb = tid / (S4_SEQ * S4_T);
    const int r  = tid - pb * (S4_SEQ * S4_T);
    const int s = r / S4_T, t = r - s * S4_T;
    xb[pb][s][t] = x[(seq0 + pb * S4_SEQ + s) * S4_T + t];
  }
  __syncthreads();

  // encoder seeds hb for both pipelines
  {
    const float ew = enc_W[hch], eb = enc_b[hch];
#pragma unroll
    for (int pb = 0; pb < S4_PB; ++pb) {
#pragma unroll
      for (int sp = 0; sp < 2; ++sp) {
        const int s = (tid >> 7) + 2 * sp;
#pragma unroll
        for (int t = 0; t < S4_T; ++t)
          hb[pb][s * S4_T + t][hch] = fmaf(xb[pb][s][t], ew, eb);
      }
    }
  }

  for (int l = 0; l < S4_NL; ++l) {
    __syncthreads();
    // ---- conv phase: A then B (independent -> ILP across pipelines) ----
    {
      const float* kp = &kws[(l * S4_H + hch) * S4_T];
      const f4 k0 = *(const f4*)(kp), k1 = *(const f4*)(kp + 4),
               k2 = *(const f4*)(kp + 8);
      const float kr[S4_T] = {k0[0], k0[1], k0[2], k0[3], k1[0], k1[1],
                              k1[2], k1[3], k2[0], k2[1], k2[2], k2[3]};
      const float dl = Dp[l * S4_H + hch];
#pragma unroll
      for (int pb = 0; pb < S4_PB; ++pb) {
#pragma unroll
        for (int sp = 0; sp < 2; ++sp) {
          const int s = (tid >> 7) + 2 * sp;
          float z[S4_T];
#pragma unroll
          for (int t = 0; t < S4_T; ++t) z[t] = hb[pb][s * S4_T + t][hch];
#pragma unroll
          for (int t = 0; t < S4_T; ++t) {
            float a = dl * z[t];
#pragma unroll
            for (int ss = 0; ss <= t; ++ss) a = fmaf(kr[t - ss], z[ss], a);
            gb[pb][s * S4_T + t][hch] = f2bf(fast_gelu(a));
          }
        }
      }
    }
    __syncthreads();
    // ---- channel mix via MFMA, A then B (B's loads overlap A's MFMAs) ----
    {
      const int w = tid >> 6;          // wave id
      const int lane = tid & 63;
      const int r = lane & 15;         // M/N index within tile
      const int q = lane >> 4;         // k-group
#pragma unroll
      for (int pb = 0; pb < S4_PB; ++pb) {
        f4 acc[2][2][3] = {};          // [p=val/gate][mi][ntile]
#pragma unroll
        for (int p = 0; p < 2; ++p) {
          s8v af[2][4];
#pragma unroll
          for (int mi = 0; mi < 2; ++mi) {
            const int o = (2 * w + mi + p * 8) * 16 + r;
            const unsigned short* wp =
                &Wbf[(size_t)(l * 2 * S4_H + o) * S4_H + q * 8];
#pragma unroll
            for (int ks = 0; ks < 4; ++ks)
              af[mi][ks] = *reinterpret_cast<const s8v*>(wp + ks * 32);
          }
#pragma unroll
          for (int n = 0; n < 3; ++n) {
#pragma unroll
            for (int ks = 0; ks < 4; ++ks) {
              const s8v bfv = *reinterpret_cast<const s8v*>(
                  &gb[pb][n * 16 + r][ks * 32 + q * 8]);
#pragma unroll
              for (int mi = 0; mi < 2; ++mi)
                acc[p][mi][n] = __builtin_amdgcn_mfma_f32_16x16x32_bf16(
                    af[mi][ks], bfv, acc[p][mi][n], 0, 0, 0);
            }
          }
        }
        // GLU + bias + residual RMW into hb (unique 16B quads per lane)
#pragma unroll
        for (int mi = 0; mi < 2; ++mi) {
          const int oV = (2 * w + mi) * 16 + q * 4;
          const f4 bV = *(const f4*)&out_b[l * 2 * S4_H + oV];
          const f4 bG = *(const f4*)&out_b[l * 2 * S4_H + S4_H + oV];
#pragma unroll
          for (int n = 0; n < 3; ++n) {
            const int tt = n * 16 + r;
            f4* hp = reinterpret_cast<f4*>(&hb[pb][tt][oV]);
            f4 hv = *hp;
#pragma unroll
            for (int j = 0; j < 4; ++j) {
              const float a = acc[0][mi][n][j] + bV[j];
              const float g = acc[1][mi][n][j] + bG[j];
              hv[j] += a * fast_sigmoid(g);
            }
            *hp = hv;
          }
        }
      }
    }
    __syncthreads();
    // ---- LayerNorm (in-place), A then B ----
    {
      const int g = tid >> 2, q = tid & 3;
      if (g < S4_TT) {
#pragma unroll
        for (int pb = 0; pb < S4_PB; ++pb) {
          float s1 = 0.f, s2 = 0.f;
#pragma unroll
          for (int j = 0; j < 8; ++j) {
            const f4 v = *(const f4*)&hb[pb][g][(q + 4 * j) * 4];
            s1 += v[0] + v[1] + v[2] + v[3];
            s2 = fmaf(v[0], v[0], s2); s2 = fmaf(v[1], v[1], s2);
            s2 = fmaf(v[2], v[2], s2); s2 = fmaf(v[3], v[3], s2);
          }
          s1 += __shfl_xor(s1, 1, 4); s1 += __shfl_xor(s1, 2, 4);
          s2 += __shfl_xor(s2, 1, 4); s2 += __shfl_xor(s2, 2, 4);
          const float mu   = s1 * (1.0f / S4_H);
          const float var  = s2 * (1.0f / S4_H) - mu * mu;
          const float rstd = rsqrtf(var + 1e-5f);
#pragma unroll
          for (int j = 0; j < 8; ++j) {
            const int e = (q + 4 * j) * 4;
            f4 v = *(const f4*)&hb[pb][g][e];
            const f4 gg = *(const f4*)&ln_g[l * S4_H + e];
            const f4 bb = *(const f4*)&ln_b[l * S4_H + e];
#pragma unroll
            for (int jj = 0; jj < 4; ++jj)
              v[jj] = fmaf((v[jj] - mu) * rstd, gg[jj], bb[jj]);
            *(f4*)&hb[pb][g][e] = v;
          }
        }
      }
    }
  }
  __syncthreads();
  // ---- output (B,H,N,T) + 1x1 conv shortcut, both pipelines ----
  {
    const float sw = sc_W[hch], sb = sc_b[hch];
#pragma unroll
    for (int pb = 0; pb < S4_PB; ++pb) {
#pragma unroll
      for (int sp = 0; sp < 2; ++sp) {
        const int s = (tid >> 7) + 2 * sp;
        const int bn = seq0 + pb * S4_SEQ + s;
        const int b = bn >> 10, n = bn & (S4_N - 1);
        float* op = out + (size_t)((b * S4_H + hch) * S4_N + n) * S4_T;
#pragma unroll
        for (int qq = 0; qq < 3; ++qq) {
          f4 o;
#pragma unroll
          for (int t4 = 0; t4 < 4; ++t4) {
            const int t = qq * 4 + t4;
            o[t4] = hb[pb][s * S4_T + t][hch] + fmaf(sw, xb[pb][s][t], sb);
          }
          *reinterpret_cast<f4*>(op + qq * 4) = o;
        }
      }
    }
  }
}

// ---------------------------------------------------------------------------
// Fallback (no workspace): round-1 fp32 kernel, inline-k variant (exact math).
// ---------------------------------------------------------------------------
#define S4F_SEQ 4
__global__ __launch_bounds__(256) void s4_main_f32(
    const float* __restrict__ x, const float* __restrict__ enc_W,
    const float* __restrict__ enc_b, const float* __restrict__ log_A_real,
    const float* __restrict__ A_imag, const float* __restrict__ C_re,
    const float* __restrict__ C_im, const float* __restrict__ log_dt,
    const float* __restrict__ Dp, const float* __restrict__ out_W,
    const float* __restrict__ out_b, const float* __restrict__ ln_g,
    const float* __restrict__ ln_b, const float* __restrict__ sc_W,
    const float* __restrict__ sc_b, float* __restrict__ out) {
  __shared__ __align__(16) float hbuf[S4F_SEQ][S4_H][S4_T];
  __shared__ __align__(16) float gbuf[S4F_SEQ][S4_H][S4_T];
  __shared__ __align__(16) float kbuf[S4_NL][S4_H][S4_T];
  __shared__ __align__(16) float xbuf[S4F_SEQ][S4_T];
  const int tid = threadIdx.x;
  const int seq0 = blockIdx.x * S4F_SEQ;
  if (tid < S4F_SEQ * S4_T) {
    const int s = tid / S4_T, t = tid - s * S4_T;
    xbuf[s][t] = x[(seq0 + s) * S4_T + t];
  }
  {
    float kk[S4_T];
    s4d_row(log_A_real, A_imag, C_re, C_im, log_dt, tid, kk);
#pragma unroll
    for (int t = 0; t < S4_T; ++t) (&kbuf[0][0][0])[tid * S4_T + t] = kk[t];
  }
  __syncthreads();
  for (int r = tid; r < S4F_SEQ * S4_H; r += 256) {
    const int s = r >> 7, h = r & (S4_H - 1);
    const float ew = enc_W[h], eb = enc_b[h];
#pragma unroll
    for (int t = 0; t < S4_T; ++t) hbuf[s][h][t] = fmaf(xbuf[s][t], ew, eb);
  }
  for (int l = 0; l < S4_NL; ++l) {
    __syncthreads();
    for (int r = tid; r < S4F_SEQ * S4_H; r += 256) {
      const int s = r >> 7, h = r & (S4_H - 1);
      float z[S4_T], kr[S4_T];
#pragma unroll
      for (int t = 0; t < S4_T; ++t) {
        z[t] = hbuf[s][h][t];
        kr[t] = kbuf[l][h][t];
      }
      const float dl = Dp[l * S4_H + h];
#pragma unroll
      for (int t = 0; t < S4_T; ++t) {
        float a = dl * z[t];
#pragma unroll
        for (int ss = 0; ss <= t; ++ss) a = fmaf(kr[t - ss], z[ss], a);
        gbuf[s][h][t] = 0.5f * a * (1.0f + erff(a * 0.70710678118654752f));
      }
    }
    __syncthreads();
    {
      const int op = tid & (S4_H - 1);
      const int sg = tid >> 7;
      const float* __restrict__ W0 = out_W + (size_t)(l * 2 * S4_H + op) * S4_H;
      const float* __restrict__ W1 = W0 + S4_H * S4_H;
      float acc0[2][S4_T], acc1[2][S4_T];
#pragma unroll
      for (int s2 = 0; s2 < 2; ++s2)
#pragma unroll
        for (int t = 0; t < S4_T; ++t) { acc0[s2][t] = 0.f; acc1[s2][t] = 0.f; }
      for (int h0 = 0; h0 < S4_H; h0 += 4) {
        const float4 w0 = *reinterpret_cast<const float4*>(W0 + h0);
        const float4 w1 = *reinterpret_cast<const float4*>(W1 + h0);
        const float w0a[4] = {w0.x, w0.y, w0.z, w0.w};
        const float w1a[4] = {w1.x, w1.y, w1.z, w1.w};
#pragma unroll
        for (int j = 0; j < 4; ++j) {
#pragma unroll
          for (int s2 = 0; s2 < 2; ++s2) {
            const float* gp = &gbuf[2 * sg + s2][h0 + j][0];
            const float4 ga = *reinterpret_cast<const float4*>(gp);
            const float4 gc = *reinterpret_cast<const float4*>(gp + 4);
            const float4 ge = *reinterpret_cast<const float4*>(gp + 8);
            const float gg[S4_T] = {ga.x, ga.y, ga.z, ga.w, gc.x, gc.y,
                                    gc.z, gc.w, ge.x, ge.y, ge.z, ge.w};
#pragma unroll
            for (int t = 0; t < S4_T; ++t) {
              acc0[s2][t] = fmaf(w0a[j], gg[t], acc0[s2][t]);
              acc1[s2][t] = fmaf(w1a[j], gg[t], acc1[s2][t]);
            }
          }
        }
      }
      const float b0 = out_b[l * 2 * S4_H + op];
      const float b1 = out_b[l * 2 * S4_H + S4_H + op];
#pragma unroll
      for (int s2 = 0; s2 < 2; ++s2) {
        const int seq = 2 * sg + s2;
#pragma unroll
        for (int t = 0; t < S4_T; ++t) {
          const float a = acc0[s2][t] + b0;
          const float g = acc1[s2][t] + b1;
          hbuf[seq][op][t] += a * (1.0f / (1.0f + expf(-g)));
        }
      }
    }
    __syncthreads();
    {
      const int col = tid >> 2;
      const int ing = tid & 3;
      if (col < S4F_SEQ * S4_T) {
        const int s = col / S4_T, t = col - s * S4_T;
        float s1 = 0.f, s2v = 0.f;
#pragma unroll
        for (int i = 0; i < S4_H / 4; ++i) {
          const float v = hbuf[s][ing * 32 + i][t];
          s1 += v;
          s2v = fmaf(v, v, s2v);
        }
        s1 += __shfl_xor(s1, 1, 4); s1 += __shfl_xor(s1, 2, 4);
        s2v += __shfl_xor(s2v, 1, 4); s2v += __shfl_xor(s2v, 2, 4);
        const float mu = s1 * (1.0f / S4_H);
        const float var = s2v * (1.0f / S4_H) - mu * mu;
        const float rstd = rsqrtf(var + 1e-5f);
#pragma unroll
        for (int i = 0; i < S4_H / 4; ++i) {
          const int h = ing * 32 + i;
          const float v = hbuf[s][h][t];
          hbuf[s][h][t] =
              fmaf((v - mu) * rstd, ln_g[l * S4_H + h], ln_b[l * S4_H + h]);
        }
      }
    }
  }
  __syncthreads();
  for (int r = tid; r < S4F_SEQ * S4_H; r += 256) {
    const int s = r >> 7, h = r & (S4_H - 1);
    const int bn = seq0 + s;
    const int b = bn >> 10, n = bn & (S4_N - 1);
    const float sw = sc_W[h], sb = sc_b[h];
#pragma unroll
    for (int q = 0; q < 3; ++q) {
      float4 o;
      const float4 hv0 = *reinterpret_cast<const float4*>(&hbuf[s][h][4 * q]);
      const float4 xv = *reinterpret_cast<const float4*>(&xbuf[s][4 * q]);
      o.x = hv0.x + fmaf(sw, xv.x, sb);
      o.y = hv0.y + fmaf(sw, xv.y, sb);
      o.z = hv0.z + fmaf(sw, xv.z, sb);
      o.w = hv0.w + fmaf(sw, xv.w, sb);
      reinterpret_cast<float4*>(out + (size_t)((b * S4_H + h) * S4_N + n) *
                                          S4_T)[q] = o;
    }
  }
}

extern "C" void kernel_launch(void* const* d_in, const int* in_sizes, int n_in,
                              void* d_out, int out_size, void* d_ws,
                              size_t ws_size, hipStream_t stream) {
  const float* x     = (const float*)d_in[0];
  const float* enc_W = (const float*)d_in[1];
  const float* enc_b = (const float*)d_in[2];
  const float* lAr   = (const float*)d_in[3];
  const float* Aim   = (const float*)d_in[4];
  const float* Cre   = (const float*)d_in[5];
  const float* Cim   = (const float*)d_in[6];
  const float* ldt   = (const float*)d_in[7];
  const float* Dp    = (const float*)d_in[8];
  const float* oW    = (const float*)d_in[9];
  const float* ob    = (const float*)d_in[10];
  const float* lg    = (const float*)d_in[11];
  const float* lb    = (const float*)d_in[12];
  const float* scW   = (const float*)d_in[13];
  const float* scb   = (const float*)d_in[14];
  float* out = (float*)d_out;

  const size_t wbytes = (size_t)(S4_NL * 2 * S4_H * S4_H) * sizeof(unsigned short); // 131072
  const size_t kbytes = (size_t)(S4_NL * S4_H * S4_T) * sizeof(float);              // 12288
  if (ws_size >= wbytes + kbytes) {
    unsigned short* Wbf = (unsigned short*)d_ws;
    float* kws = (float*)((char*)d_ws + wbytes);
    s4_prep<<<64, 256, 0, stream>>>(oW, lAr, Aim, Cre, Cim, ldt, Wbf, kws);
    s4_mfma2<<<S4_BN / (S4_PB * S4_SEQ), 256, 0, stream>>>(
        x, enc_W, enc_b, Dp, ob, lg, lb, scW, scb, Wbf, kws, out);
  } else {
    s4_main_f32<<<S4_BN / S4F_SEQ, 256, 0, stream>>>(
        x, enc_W, enc_b, lAr, Aim, Cre, Cim, ldt, Dp, oW, ob, lg, lb, scW,
        scb, out);
  }
}

// Round 9
// 142.665 us; speedup vs baseline: 2.5934x; 1.1094x over previous
//
#include <hip/hip_runtime.h>
#include <math.h>

#define S4_H   128
#define S4_HP  136          // padded leading dim (dword stride 136 ≡ 8 mod 32)
#define S4_T   12
#define S4_TT  48           // 4 seqs * 12 timesteps
#define S4_S2  32
#define S4_SEQ 4
#define S4_NL  2
#define S4_N   1024
#define S4_BN  (16 * 1024)

typedef float f4 __attribute__((ext_vector_type(4)));
typedef short s8v __attribute__((ext_vector_type(8)));   // 8 bf16 bit-patterns

__device__ __forceinline__ unsigned short f2bf(float f) {
  unsigned int u = __builtin_bit_cast(unsigned int, f);
  u += 0x7fffu + ((u >> 16) & 1u);   // RNE
  return (unsigned short)(u >> 16);
}

// gelu(x) ~= x * sigmoid(1.5957691x(1 + 0.044715x^2))  (tanh form)
__device__ __forceinline__ float fast_gelu(float x) {
  const float u = 1.5957691216057308f * x * fmaf(0.044715f, x * x, 1.0f);
  return x * __builtin_amdgcn_rcpf(1.0f + __expf(-u));
}
__device__ __forceinline__ float fast_sigmoid(float g) {
  return __builtin_amdgcn_rcpf(1.0f + __expf(-g));
}

// ---------------------------------------------------------------------------
// S4D kernel row: k[h][t] = 2*Re( sum_n C_n * exp(dtA_n)^t ), ZOH discretized.
// ---------------------------------------------------------------------------
__device__ __forceinline__ void s4d_row(const float* __restrict__ log_A_real,
                                        const float* __restrict__ A_imag,
                                        const float* __restrict__ C_re,
                                        const float* __restrict__ C_im,
                                        const float* __restrict__ log_dt,
                                        int lh, float* kk) {
  const float dt = expf(log_dt[lh]);
#pragma unroll
  for (int t = 0; t < S4_T; ++t) kk[t] = 0.f;
  const int base = lh * S4_S2;
  for (int n = 0; n < S4_S2; ++n) {
    const float ar = -expf(log_A_real[base + n]);
    const float ai = A_imag[base + n];
    const float m  = expf(ar * dt);
    const float di = ai * dt;
    float sdi, cdi;
    sincosf(di, &sdi, &cdi);
    const float er = m * cdi, ei = m * sdi;           // exp(dt*A)
    const float inv = 1.0f / (ar * ar + ai * ai);
    const float x0 = er - 1.0f;
    const float qr = (x0 * ar + ei * ai) * inv;       // (exp(dtA)-1)/A
    const float qi = (ei * ar - x0 * ai) * inv;
    const float c0r = C_re[base + n], c0i = C_im[base + n];
    const float cr = c0r * qr - c0i * qi;             // C_tilde
    const float ci = c0r * qi + c0i * qr;
    float vr = 1.f, vi = 0.f;                         // V = exp(dtA)^t
#pragma unroll
    for (int t = 0; t < S4_T; ++t) {
      kk[t] = fmaf(cr, vr, fmaf(-ci, vi, kk[t]));
      const float nvr = vr * er - vi * ei;
      vi = vr * ei + vi * er;
      vr = nvr;
    }
  }
#pragma unroll
  for (int t = 0; t < S4_T; ++t) kk[t] *= 2.0f;
}

// prep: W fp32 -> bf16 bits in ws, and S4D kernel k into ws.
__global__ __launch_bounds__(256) void s4_prep(
    const float* __restrict__ oW, const float* __restrict__ lAr,
    const float* __restrict__ Aim, const float* __restrict__ Cre,
    const float* __restrict__ Cim, const float* __restrict__ ldt,
    unsigned short* __restrict__ Wbf, float* __restrict__ kout) {
  const int tid = blockIdx.x * 256 + (int)threadIdx.x;
  const int i = tid * 4;
  if (i < S4_NL * 2 * S4_H * S4_H) {
    const f4 v = *reinterpret_cast<const f4*>(&oW[i]);
    ushort4 o;
    o.x = f2bf(v[0]); o.y = f2bf(v[1]); o.z = f2bf(v[2]); o.w = f2bf(v[3]);
    *reinterpret_cast<ushort4*>(&Wbf[i]) = o;
  }
  if (tid < S4_NL * S4_H) {
    float kk[S4_T];
    s4d_row(lAr, Aim, Cre, Cim, ldt, tid, kk);
#pragma unroll
    for (int t = 0; t < S4_T; ++t) kout[tid * S4_T + t] = kk[t];
  }
}

// ---------------------------------------------------------------------------
// Fused S4 block, 512 threads (8 waves), R3 memory patterns preserved.
// Per-thread work halved; VGPR forced <=64 for 32 waves/CU.
// ---------------------------------------------------------------------------
__global__ __launch_bounds__(512, 8) void s4_512(
    const float* __restrict__ x, const float* __restrict__ enc_W,
    const float* __restrict__ enc_b, const float* __restrict__ Dp,
    const float* __restrict__ out_b, const float* __restrict__ ln_g,
    const float* __restrict__ ln_b, const float* __restrict__ sc_W,
    const float* __restrict__ sc_b, const unsigned short* __restrict__ Wbf,
    const float* __restrict__ kws, float* __restrict__ out) {
  __shared__ __align__(16) float hb[S4_TT][S4_HP];           // 26112 B (fp32)
  __shared__ __align__(16) unsigned short gb[S4_TT][S4_HP];  // 13056 B (bf16)
  __shared__ __align__(16) float xb[S4_SEQ][S4_T];           // 192 B

  const int tid  = threadIdx.x;
  const int w    = tid >> 6;          // wave 0..7
  const int lane = tid & 63;
  const int s    = tid >> 7;          // owned sequence (conv/output), 0..3
  const int h    = tid & (S4_H - 1);  // owned channel (conv/output)
  const int seq0 = blockIdx.x * S4_SEQ;

  if (tid < S4_SEQ * S4_T) {
    const int ss = tid / S4_T, t = tid - ss * S4_T;
    xb[ss][t] = x[(seq0 + ss) * S4_T + t];
  }
  __syncthreads();

  for (int l = 0; l < S4_NL; ++l) {
    // ---- conv phase (1 row per thread); l==0 fuses encoder & seeds hb ----
    {
      const float* kp = &kws[(l * S4_H + h) * S4_T];
      const f4 k0 = *(const f4*)(kp), k1 = *(const f4*)(kp + 4),
               k2 = *(const f4*)(kp + 8);
      const float kr[S4_T] = {k0[0], k0[1], k0[2], k0[3], k1[0], k1[1],
                              k1[2], k1[3], k2[0], k2[1], k2[2], k2[3]};
      const float dl = Dp[l * S4_H + h];
      float z[S4_T];
      if (l == 0) {
        const float ew = enc_W[h], eb = enc_b[h];
#pragma unroll
        for (int t = 0; t < S4_T; ++t) {
          z[t] = fmaf(xb[s][t], ew, eb);
          hb[s * S4_T + t][h] = z[t];
        }
      } else {
#pragma unroll
        for (int t = 0; t < S4_T; ++t) z[t] = hb[s * S4_T + t][h];
      }
#pragma unroll
      for (int t = 0; t < S4_T; ++t) {
        float a = dl * z[t];
#pragma unroll
        for (int ss = 0; ss <= t; ++ss) a = fmaf(kr[t - ss], z[ss], a);
        gb[s * S4_T + t][h] = f2bf(fast_gelu(a));
      }
    }
    __syncthreads();
    // ---- channel mix: wave w owns val tile w, gate tile 8+w ----
    {
      const int r = lane & 15;        // N index (tt within tile) / A row offset
      const int q = lane >> 4;        // k-group / D row group
      f4 accV[3] = {}, accG[3] = {};
      const unsigned short* WL = Wbf + (size_t)l * 2 * S4_H * S4_H;
      const unsigned short* wVp = WL + (size_t)(w * 16 + r) * S4_H + q * 8;
      const unsigned short* wGp = WL + (size_t)((8 + w) * 16 + r) * S4_H + q * 8;
#pragma unroll
      for (int ks = 0; ks < 4; ++ks) {
        const s8v afV = *(const s8v*)(wVp + ks * 32);
        const s8v afG = *(const s8v*)(wGp + ks * 32);
#pragma unroll
        for (int n = 0; n < 3; ++n) {
          const s8v bfv =
              *(const s8v*)(&gb[n * 16 + r][ks * 32 + q * 8]);
          accV[n] = __builtin_amdgcn_mfma_f32_16x16x32_bf16(afV, bfv, accV[n],
                                                            0, 0, 0);
          accG[n] = __builtin_amdgcn_mfma_f32_16x16x32_bf16(afG, bfv, accG[n],
                                                            0, 0, 0);
        }
      }
      // GLU + bias + residual RMW into hb (unique 16B quads per lane)
      const int oV = w * 16 + 4 * q;
      const f4 bV = *(const f4*)&out_b[l * 2 * S4_H + oV];
      const f4 bG = *(const f4*)&out_b[l * 2 * S4_H + S4_H + oV];
#pragma unroll
      for (int n = 0; n < 3; ++n) {
        f4* hp = reinterpret_cast<f4*>(&hb[n * 16 + r][oV]);
        f4 hv = *hp;
#pragma unroll
        for (int j = 0; j < 4; ++j) {
          const float a = accV[n][j] + bV[j];
          const float g = accG[n][j] + bG[j];
          hv[j] += a * fast_sigmoid(g);
        }
        *hp = hv;
      }
    }
    __syncthreads();
    // ---- LayerNorm in-place: 8 lanes per tt column, two-pass (low regs) ----
    {
      const int col = tid >> 3;       // 0..63 (cols >=48 idle)
      const int q8  = tid & 7;
      if (col < S4_TT) {
        float s1 = 0.f, s2 = 0.f;
#pragma unroll
        for (int j = 0; j < 4; ++j) {
          const f4 v = *(const f4*)&hb[col][(q8 + 8 * j) * 4];
          s1 += v[0] + v[1] + v[2] + v[3];
          s2 = fmaf(v[0], v[0], s2); s2 = fmaf(v[1], v[1], s2);
          s2 = fmaf(v[2], v[2], s2); s2 = fmaf(v[3], v[3], s2);
        }
        s1 += __shfl_xor(s1, 1, 8); s1 += __shfl_xor(s1, 2, 8);
        s1 += __shfl_xor(s1, 4, 8);
        s2 += __shfl_xor(s2, 1, 8); s2 += __shfl_xor(s2, 2, 8);
        s2 += __shfl_xor(s2, 4, 8);
        const float mu   = s1 * (1.0f / S4_H);
        const float var  = s2 * (1.0f / S4_H) - mu * mu;
        const float rstd = rsqrtf(var + 1e-5f);
#pragma unroll
        for (int j = 0; j < 4; ++j) {
          const int e = (q8 + 8 * j) * 4;
          f4 v = *(const f4*)&hb[col][e];
          const f4 gg = *(const f4*)&ln_g[l * S4_H + e];
          const f4 bb = *(const f4*)&ln_b[l * S4_H + e];
#pragma unroll
          for (int jj = 0; jj < 4; ++jj)
            v[jj] = fmaf((v[jj] - mu) * rstd, gg[jj], bb[jj]);
          *(f4*)&hb[col][e] = v;
        }
      }
    }
    __syncthreads();
  }
  // ---- output (B,H,N,T) + 1x1 conv shortcut (1 row per thread) ----
  {
    const float sw = sc_W[h], sb = sc_b[h];
    const int bn = seq0 + s;
    const int b = bn >> 10, n = bn & (S4_N - 1);
    float* op = out + (size_t)((b * S4_H + h) * S4_N + n) * S4_T;
#pragma unroll
    for (int qq = 0; qq < 3; ++qq) {
      f4 o;
#pragma unroll
      for (int t4 = 0; t4 < 4; ++t4) {
        const int t = qq * 4 + t4;
        o[t4] = hb[s * S4_T + t][h] + fmaf(sw, xb[s][t], sb);
      }
      *reinterpret_cast<f4*>(op + qq * 4) = o;
    }
  }
}

// ---------------------------------------------------------------------------
// Fallback (no workspace): round-1 fp32 kernel, inline-k variant (exact math).
// ---------------------------------------------------------------------------
#define S4F_SEQ 4
__global__ __launch_bounds__(256) void s4_main_f32(
    const float* __restrict__ x, const float* __restrict__ enc_W,
    const float* __restrict__ enc_b, const float* __restrict__ log_A_real,
    const float* __restrict__ A_imag, const float* __restrict__ C_re,
    const float* __restrict__ C_im, const float* __restrict__ log_dt,
    const float* __restrict__ Dp, const float* __restrict__ out_W,
    const float* __restrict__ out_b, const float* __restrict__ ln_g,
    const float* __restrict__ ln_b, const float* __restrict__ sc_W,
    const float* __restrict__ sc_b, float* __restrict__ out) {
  __shared__ __align__(16) float hbuf[S4F_SEQ][S4_H][S4_T];
  __shared__ __align__(16) float gbuf[S4F_SEQ][S4_H][S4_T];
  __shared__ __align__(16) float kbuf[S4_NL][S4_H][S4_T];
  __shared__ __align__(16) float xbuf[S4F_SEQ][S4_T];
  const int tid = threadIdx.x;
  const int seq0 = blockIdx.x * S4F_SEQ;
  if (tid < S4F_SEQ * S4_T) {
    const int s = tid / S4_T, t = tid - s * S4_T;
    xbuf[s][t] = x[(seq0 + s) * S4_T + t];
  }
  {
    float kk[S4_T];
    s4d_row(log_A_real, A_imag, C_re, C_im, log_dt, tid, kk);
#pragma unroll
    for (int t = 0; t < S4_T; ++t) (&kbuf[0][0][0])[tid * S4_T + t] = kk[t];
  }
  __syncthreads();
  for (int r = tid; r < S4F_SEQ * S4_H; r += 256) {
    const int s = r >> 7, h = r & (S4_H - 1);
    const float ew = enc_W[h], eb = enc_b[h];
#pragma unroll
    for (int t = 0; t < S4_T; ++t) hbuf[s][h][t] = fmaf(xbuf[s][t], ew, eb);
  }
  for (int l = 0; l < S4_NL; ++l) {
    __syncthreads();
    for (int r = tid; r < S4F_SEQ * S4_H; r += 256) {
      const int s = r >> 7, h = r & (S4_H - 1);
      float z[S4_T], kr[S4_T];
#pragma unroll
      for (int t = 0; t < S4_T; ++t) {
        z[t] = hbuf[s][h][t];
        kr[t] = kbuf[l][h][t];
      }
      const float dl = Dp[l * S4_H + h];
#pragma unroll
      for (int t = 0; t < S4_T; ++t) {
        float a = dl * z[t];
#pragma unroll
        for (int ss = 0; ss <= t; ++ss) a = fmaf(kr[t - ss], z[ss], a);
        gbuf[s][h][t] = 0.5f * a * (1.0f + erff(a * 0.70710678118654752f));
      }
    }
    __syncthreads();
    {
      const int op = tid & (S4_H - 1);
      const int sg = tid >> 7;
      const float* __restrict__ W0 = out_W + (size_t)(l * 2 * S4_H + op) * S4_H;
      const float* __restrict__ W1 = W0 + S4_H * S4_H;
      float acc0[2][S4_T], acc1[2][S4_T];
#pragma unroll
      for (int s2 = 0; s2 < 2; ++s2)
#pragma unroll
        for (int t = 0; t < S4_T; ++t) { acc0[s2][t] = 0.f; acc1[s2][t] = 0.f; }
      for (int h0 = 0; h0 < S4_H; h0 += 4) {
        const float4 w0 = *reinterpret_cast<const float4*>(W0 + h0);
        const float4 w1 = *reinterpret_cast<const float4*>(W1 + h0);
        const float w0a[4] = {w0.x, w0.y, w0.z, w0.w};
        const float w1a[4] = {w1.x, w1.y, w1.z, w1.w};
#pragma unroll
        for (int j = 0; j < 4; ++j) {
#pragma unroll
          for (int s2 = 0; s2 < 2; ++s2) {
            const float* gp = &gbuf[2 * sg + s2][h0 + j][0];
            const float4 ga = *reinterpret_cast<const float4*>(gp);
            const float4 gc = *reinterpret_cast<const float4*>(gp + 4);
            const float4 ge = *reinterpret_cast<const float4*>(gp + 8);
            const float gg[S4_T] = {ga.x, ga.y, ga.z, ga.w, gc.x, gc.y,
                                    gc.z, gc.w, ge.x, ge.y, ge.z, ge.w};
#pragma unroll
            for (int t = 0; t < S4_T; ++t) {
              acc0[s2][t] = fmaf(w0a[j], gg[t], acc0[s2][t]);
              acc1[s2][t] = fmaf(w1a[j], gg[t], acc1[s2][t]);
            }
          }
        }
      }
      const float b0 = out_b[l * 2 * S4_H + op];
      const float b1 = out_b[l * 2 * S4_H + S4_H + op];
#pragma unroll
      for (int s2 = 0; s2 < 2; ++s2) {
        const int seq = 2 * sg + s2;
#pragma unroll
        for (int t = 0; t < S4_T; ++t) {
          const float a = acc0[s2][t] + b0;
          const float g = acc1[s2][t] + b1;
          hbuf[seq][op][t] += a * (1.0f / (1.0f + expf(-g)));
        }
      }
    }
    __syncthreads();
    {
      const int col = tid >> 2;
      const int ing = tid & 3;
      if (col < S4F_SEQ * S4_T) {
        const int s = col / S4_T, t = col - s * S4_T;
        float s1 = 0.f, s2v = 0.f;
#pragma unroll
        for (int i = 0; i < S4_H / 4; ++i) {
          const float v = hbuf[s][ing * 32 + i][t];
          s1 += v;
          s2v = fmaf(v, v, s2v);
        }
        s1 += __shfl_xor(s1, 1, 4); s1 += __shfl_xor(s1, 2, 4);
        s2v += __shfl_xor(s2v, 1, 4); s2v += __shfl_xor(s2v, 2, 4);
        const float mu = s1 * (1.0f / S4_H);
        const float var = s2v * (1.0f / S4_H) - mu * mu;
        const float rstd = rsqrtf(var + 1e-5f);
#pragma unroll
        for (int i = 0; i < S4_H / 4; ++i) {
          const int h = ing * 32 + i;
          const float v = hbuf[s][h][t];
          hbuf[s][h][t] =
              fmaf((v - mu) * rstd, ln_g[l * S4_H + h], ln_b[l * S4_H + h]);
        }
      }
    }
  }
  __syncthreads();
  for (int r = tid; r < S4F_SEQ * S4_H; r += 256) {
    const int s = r >> 7, h = r & (S4_H - 1);
    const int bn = seq0 + s;
    const int b = bn >> 10, n = bn & (S4_N - 1);
    const float sw = sc_W[h], sb = sc_b[h];
#pragma unroll
    for (int q = 0; q < 3; ++q) {
      float4 o;
      const float4 hv0 = *reinterpret_cast<const float4*>(&hbuf[s][h][4 * q]);
      const float4 xv = *reinterpret_cast<const float4*>(&xbuf[s][4 * q]);
      o.x = hv0.x + fmaf(sw, xv.x, sb);
      o.y = hv0.y + fmaf(sw, xv.y, sb);
      o.z = hv0.z + fmaf(sw, xv.z, sb);
      o.w = hv0.w + fmaf(sw, xv.w, sb);
      reinterpret_cast<float4*>(out + (size_t)((b * S4_H + h) * S4_N + n) *
                                          S4_T)[q] = o;
    }
  }
}

extern "C" void kernel_launch(void* const* d_in, const int* in_sizes, int n_in,
                              void* d_out, int out_size, void* d_ws,
                              size_t ws_size, hipStream_t stream) {
  const float* x     = (const float*)d_in[0];
  const float* enc_W = (const float*)d_in[1];
  const float* enc_b = (const float*)d_in[2];
  const float* lAr   = (const float*)d_in[3];
  const float* Aim   = (const float*)d_in[4];
  const float* Cre   = (const float*)d_in[5];
  const float* Cim   = (const float*)d_in[6];
  const float* ldt   = (const float*)d_in[7];
  const float* Dp    = (const float*)d_in[8];
  const float* oW    = (const float*)d_in[9];
  const float* ob    = (const float*)d_in[10];
  const float* lg    = (const float*)d_in[11];
  const float* lb    = (const float*)d_in[12];
  const float* scW   = (const float*)d_in[13];
  const float* scb   = (const float*)d_in[14];
  float* out = (float*)d_out;

  const size_t wbytes = (size_t)(S4_NL * 2 * S4_H * S4_H) * sizeof(unsigned short); // 131072
  const size_t kbytes = (size_t)(S4_NL * S4_H * S4_T) * sizeof(float);              // 12288
  if (ws_size >= wbytes + kbytes) {
    unsigned short* Wbf = (unsigned short*)d_ws;
    float* kws = (float*)((char*)d_ws + wbytes);
    s4_prep<<<64, 256, 0, stream>>>(oW, lAr, Aim, Cre, Cim, ldt, Wbf, kws);
    s4_512<<<S4_BN / S4_SEQ, 512, 0, stream>>>(x, enc_W, enc_b, Dp, ob, lg,
                                               lb, scW, scb, Wbf, kws, out);
  } else {
    s4_main_f32<<<S4_BN / S4F_SEQ, 256, 0, stream>>>(
        x, enc_W, enc_b, lAr, Aim, Cre, Cim, ldt, Dp, oW, ob, lg, lb, scW,
        scb, out);
  }
}

// Round 10
// 135.399 us; speedup vs baseline: 2.7326x; 1.0537x over previous
//
#include <hip/hip_runtime.h>
#include <math.h>

#define S4_H   128
#define S4_HP  136          // padded leading dim (dword stride 136 ≡ 8 mod 32)
#define S4_T   12
#define S4_TT  48           // 4 seqs * 12 timesteps
#define S4_S2  32
#define S4_SEQ 4
#define S4_NL  2
#define S4_N   1024
#define S4_BN  (16 * 1024)

typedef float f4 __attribute__((ext_vector_type(4)));
typedef short s8v __attribute__((ext_vector_type(8)));   // 8 bf16 bit-patterns

__device__ __forceinline__ unsigned short f2bf(float f) {
  unsigned int u = __builtin_bit_cast(unsigned int, f);
  u += 0x7fffu + ((u >> 16) & 1u);   // RNE
  return (unsigned short)(u >> 16);
}

// gelu(x) ~= x * sigmoid(1.5957691x(1 + 0.044715x^2))  (tanh form)
__device__ __forceinline__ float fast_gelu(float x) {
  const float u = 1.5957691216057308f * x * fmaf(0.044715f, x * x, 1.0f);
  return x * __builtin_amdgcn_rcpf(1.0f + __expf(-u));
}
__device__ __forceinline__ float fast_sigmoid(float g) {
  return __builtin_amdgcn_rcpf(1.0f + __expf(-g));
}

// ---------------------------------------------------------------------------
// S4D kernel row: k[h][t] = 2*Re( sum_n C_n * exp(dtA_n)^t ), ZOH discretized.
// ---------------------------------------------------------------------------
__device__ __forceinline__ void s4d_row(const float* __restrict__ log_A_real,
                                        const float* __restrict__ A_imag,
                                        const float* __restrict__ C_re,
                                        const float* __restrict__ C_im,
                                        const float* __restrict__ log_dt,
                                        int lh, float* kk) {
  const float dt = expf(log_dt[lh]);
#pragma unroll
  for (int t = 0; t < S4_T; ++t) kk[t] = 0.f;
  const int base = lh * S4_S2;
  for (int n = 0; n < S4_S2; ++n) {
    const float ar = -expf(log_A_real[base + n]);
    const float ai = A_imag[base + n];
    const float m  = expf(ar * dt);
    const float di = ai * dt;
    float sdi, cdi;
    sincosf(di, &sdi, &cdi);
    const float er = m * cdi, ei = m * sdi;           // exp(dt*A)
    const float inv = 1.0f / (ar * ar + ai * ai);
    const float x0 = er - 1.0f;
    const float qr = (x0 * ar + ei * ai) * inv;       // (exp(dtA)-1)/A
    const float qi = (ei * ar - x0 * ai) * inv;
    const float c0r = C_re[base + n], c0i = C_im[base + n];
    const float cr = c0r * qr - c0i * qi;             // C_tilde
    const float ci = c0r * qi + c0i * qr;
    float vr = 1.f, vi = 0.f;                         // V = exp(dtA)^t
#pragma unroll
    for (int t = 0; t < S4_T; ++t) {
      kk[t] = fmaf(cr, vr, fmaf(-ci, vi, kk[t]));
      const float nvr = vr * er - vi * ei;
      vi = vr * ei + vi * er;
      vr = nvr;
    }
  }
#pragma unroll
  for (int t = 0; t < S4_T; ++t) kk[t] *= 2.0f;
}

// prep: W fp32 -> bf16 bits in ws, and S4D kernel k into ws.
__global__ __launch_bounds__(256) void s4_prep(
    const float* __restrict__ oW, const float* __restrict__ lAr,
    const float* __restrict__ Aim, const float* __restrict__ Cre,
    const float* __restrict__ Cim, const float* __restrict__ ldt,
    unsigned short* __restrict__ Wbf, float* __restrict__ kout) {
  const int tid = blockIdx.x * 256 + (int)threadIdx.x;
  const int i = tid * 4;
  if (i < S4_NL * 2 * S4_H * S4_H) {
    const f4 v = *reinterpret_cast<const f4*>(&oW[i]);
    ushort4 o;
    o.x = f2bf(v[0]); o.y = f2bf(v[1]); o.z = f2bf(v[2]); o.w = f2bf(v[3]);
    *reinterpret_cast<ushort4*>(&Wbf[i]) = o;
  }
  if (tid < S4_NL * S4_H) {
    float kk[S4_T];
    s4d_row(lAr, Aim, Cre, Cim, ldt, tid, kk);
#pragma unroll
    for (int t = 0; t < S4_T; ++t) kout[tid * S4_T + t] = kk[t];
  }
}

// ---------------------------------------------------------------------------
// Fused S4 block, 512 threads (8 waves), R3 memory patterns for hb/gb.
// Output phase: chunk-remapped so each wave store instruction covers
// consecutive 16-B chunks of contiguous 192-B h-runs (sector-aligned,
// no partial-line RMW regardless of wave drift).
// ---------------------------------------------------------------------------
__global__ __launch_bounds__(512, 8) void s4_512(
    const float* __restrict__ x, const float* __restrict__ enc_W,
    const float* __restrict__ enc_b, const float* __restrict__ Dp,
    const float* __restrict__ out_b, const float* __restrict__ ln_g,
    const float* __restrict__ ln_b, const float* __restrict__ sc_W,
    const float* __restrict__ sc_b, const unsigned short* __restrict__ Wbf,
    const float* __restrict__ kws, float* __restrict__ out) {
  __shared__ __align__(16) float hb[S4_TT][S4_HP];           // 26112 B (fp32)
  __shared__ __align__(16) unsigned short gb[S4_TT][S4_HP];  // 13056 B (bf16)
  __shared__ __align__(16) float xb[S4_SEQ][S4_T];           // 192 B

  const int tid  = threadIdx.x;
  const int w    = tid >> 6;          // wave 0..7
  const int lane = tid & 63;
  const int s    = tid >> 7;          // owned sequence (conv), 0..3
  const int h    = tid & (S4_H - 1);  // owned channel (conv)
  const int seq0 = blockIdx.x * S4_SEQ;

  if (tid < S4_SEQ * S4_T) {
    const int ss = tid / S4_T, t = tid - ss * S4_T;
    xb[ss][t] = x[(seq0 + ss) * S4_T + t];
  }
  __syncthreads();

  for (int l = 0; l < S4_NL; ++l) {
    // ---- conv phase (1 row per thread); l==0 fuses encoder & seeds hb ----
    {
      const float* kp = &kws[(l * S4_H + h) * S4_T];
      const f4 k0 = *(const f4*)(kp), k1 = *(const f4*)(kp + 4),
               k2 = *(const f4*)(kp + 8);
      const float kr[S4_T] = {k0[0], k0[1], k0[2], k0[3], k1[0], k1[1],
                              k1[2], k1[3], k2[0], k2[1], k2[2], k2[3]};
      const float dl = Dp[l * S4_H + h];
      float z[S4_T];
      if (l == 0) {
        const float ew = enc_W[h], eb = enc_b[h];
#pragma unroll
        for (int t = 0; t < S4_T; ++t) {
          z[t] = fmaf(xb[s][t], ew, eb);
          hb[s * S4_T + t][h] = z[t];
        }
      } else {
#pragma unroll
        for (int t = 0; t < S4_T; ++t) z[t] = hb[s * S4_T + t][h];
      }
#pragma unroll
      for (int t = 0; t < S4_T; ++t) {
        float a = dl * z[t];
#pragma unroll
        for (int ss = 0; ss <= t; ++ss) a = fmaf(kr[t - ss], z[ss], a);
        gb[s * S4_T + t][h] = f2bf(fast_gelu(a));
      }
    }
    __syncthreads();
    // ---- channel mix: wave w owns val tile w, gate tile 8+w ----
    {
      const int r = lane & 15;        // N index (tt within tile) / A row offset
      const int q = lane >> 4;        // k-group / D row group
      f4 accV[3] = {}, accG[3] = {};
      const unsigned short* WL = Wbf + (size_t)l * 2 * S4_H * S4_H;
      const unsigned short* wVp = WL + (size_t)(w * 16 + r) * S4_H + q * 8;
      const unsigned short* wGp = WL + (size_t)((8 + w) * 16 + r) * S4_H + q * 8;
#pragma unroll
      for (int ks = 0; ks < 4; ++ks) {
        const s8v afV = *(const s8v*)(wVp + ks * 32);
        const s8v afG = *(const s8v*)(wGp + ks * 32);
#pragma unroll
        for (int n = 0; n < 3; ++n) {
          const s8v bfv =
              *(const s8v*)(&gb[n * 16 + r][ks * 32 + q * 8]);
          accV[n] = __builtin_amdgcn_mfma_f32_16x16x32_bf16(afV, bfv, accV[n],
                                                            0, 0, 0);
          accG[n] = __builtin_amdgcn_mfma_f32_16x16x32_bf16(afG, bfv, accG[n],
                                                            0, 0, 0);
        }
      }
      // GLU + bias + residual RMW into hb (unique 16B quads per lane)
      const int oV = w * 16 + 4 * q;
      const f4 bV = *(const f4*)&out_b[l * 2 * S4_H + oV];
      const f4 bG = *(const f4*)&out_b[l * 2 * S4_H + S4_H + oV];
#pragma unroll
      for (int n = 0; n < 3; ++n) {
        f4* hp = reinterpret_cast<f4*>(&hb[n * 16 + r][oV]);
        f4 hv = *hp;
#pragma unroll
        for (int j = 0; j < 4; ++j) {
          const float a = accV[n][j] + bV[j];
          const float g = accG[n][j] + bG[j];
          hv[j] += a * fast_sigmoid(g);
        }
        *hp = hv;
      }
    }
    __syncthreads();
    // ---- LayerNorm in-place: 8 lanes per tt column ----
    {
      const int col = tid >> 3;       // 0..63 (cols >=48 idle)
      const int q8  = tid & 7;
      if (col < S4_TT) {
        float s1 = 0.f, s2 = 0.f;
#pragma unroll
        for (int j = 0; j < 4; ++j) {
          const f4 v = *(const f4*)&hb[col][(q8 + 8 * j) * 4];
          s1 += v[0] + v[1] + v[2] + v[3];
          s2 = fmaf(v[0], v[0], s2); s2 = fmaf(v[1], v[1], s2);
          s2 = fmaf(v[2], v[2], s2); s2 = fmaf(v[3], v[3], s2);
        }
        s1 += __shfl_xor(s1, 1, 8); s1 += __shfl_xor(s1, 2, 8);
        s1 += __shfl_xor(s1, 4, 8);
        s2 += __shfl_xor(s2, 1, 8); s2 += __shfl_xor(s2, 2, 8);
        s2 += __shfl_xor(s2, 4, 8);
        const float mu   = s1 * (1.0f / S4_H);
        const float var  = s2 * (1.0f / S4_H) - mu * mu;
        const float rstd = rsqrtf(var + 1e-5f);
#pragma unroll
        for (int j = 0; j < 4; ++j) {
          const int e = (q8 + 8 * j) * 4;
          f4 v = *(const f4*)&hb[col][e];
          const f4 gg = *(const f4*)&ln_g[l * S4_H + e];
          const f4 bb = *(const f4*)&ln_b[l * S4_H + e];
#pragma unroll
          for (int jj = 0; jj < 4; ++jj)
            v[jj] = fmaf((v[jj] - mu) * rstd, gg[jj], bb[jj]);
          *(f4*)&hb[col][e] = v;
        }
      }
    }
    __syncthreads();
  }
  // ---- output: chunk-remapped, sector-aligned coalesced writes ----
  // Block output = 128 h-runs x 192 B contiguous (seqs n0..n0+3 per h).
  // Chunk c = h*12 + j covers floats e = 4j..4j+3 of run h (e = s*12+t = tt).
  {
    const int b  = seq0 >> 10;             // batch (block never spans b)
    const int n0 = seq0 & (S4_N - 1);
    const float* xbf = &xb[0][0];
#pragma unroll
    for (int k = 0; k < 3; ++k) {
      const int c  = tid + 512 * k;        // 0..1535
      const int hh = c / 12;               // magic-mul division
      const int j  = c - 12 * hh;
      const float sw = sc_W[hh], sb = sc_b[hh];
      const f4 xc = *(const f4*)&xbf[4 * j];   // x[e] for e = 4j..4j+3
      f4 o;
#pragma unroll
      for (int i = 0; i < 4; ++i)
        o[i] = hb[4 * j + i][hh] + fmaf(sw, xc[i], sb);
      float* op = out + (size_t)((b * S4_H + hh) * S4_N + n0) * S4_T + 4 * j;
      *reinterpret_cast<f4*>(op) = o;
    }
  }
}

// ---------------------------------------------------------------------------
// Fallback (no workspace): round-1 fp32 kernel, inline-k variant (exact math).
// ---------------------------------------------------------------------------
#define S4F_SEQ 4
__global__ __launch_bounds__(256) void s4_main_f32(
    const float* __restrict__ x, const float* __restrict__ enc_W,
    const float* __restrict__ enc_b, const float* __restrict__ log_A_real,
    const float* __restrict__ A_imag, const float* __restrict__ C_re,
    const float* __restrict__ C_im, const float* __restrict__ log_dt,
    const float* __restrict__ Dp, const float* __restrict__ out_W,
    const float* __restrict__ out_b, const float* __restrict__ ln_g,
    const float* __restrict__ ln_b, const float* __restrict__ sc_W,
    const float* __restrict__ sc_b, float* __restrict__ out) {
  __shared__ __align__(16) float hbuf[S4F_SEQ][S4_H][S4_T];
  __shared__ __align__(16) float gbuf[S4F_SEQ][S4_H][S4_T];
  __shared__ __align__(16) float kbuf[S4_NL][S4_H][S4_T];
  __shared__ __align__(16) float xbuf[S4F_SEQ][S4_T];
  const int tid = threadIdx.x;
  const int seq0 = blockIdx.x * S4F_SEQ;
  if (tid < S4F_SEQ * S4_T) {
    const int s = tid / S4_T, t = tid - s * S4_T;
    xbuf[s][t] = x[(seq0 + s) * S4_T + t];
  }
  {
    float kk[S4_T];
    s4d_row(log_A_real, A_imag, C_re, C_im, log_dt, tid, kk);
#pragma unroll
    for (int t = 0; t < S4_T; ++t) (&kbuf[0][0][0])[tid * S4_T + t] = kk[t];
  }
  __syncthreads();
  for (int r = tid; r < S4F_SEQ * S4_H; r += 256) {
    const int s = r >> 7, h = r & (S4_H - 1);
    const float ew = enc_W[h], eb = enc_b[h];
#pragma unroll
    for (int t = 0; t < S4_T; ++t) hbuf[s][h][t] = fmaf(xbuf[s][t], ew, eb);
  }
  for (int l = 0; l < S4_NL; ++l) {
    __syncthreads();
    for (int r = tid; r < S4F_SEQ * S4_H; r += 256) {
      const int s = r >> 7, h = r & (S4_H - 1);
      float z[S4_T], kr[S4_T];
#pragma unroll
      for (int t = 0; t < S4_T; ++t) {
        z[t] = hbuf[s][h][t];
        kr[t] = kbuf[l][h][t];
      }
      const float dl = Dp[l * S4_H + h];
#pragma unroll
      for (int t = 0; t < S4_T; ++t) {
        float a = dl * z[t];
#pragma unroll
        for (int ss = 0; ss <= t; ++ss) a = fmaf(kr[t - ss], z[ss], a);
        gbuf[s][h][t] = 0.5f * a * (1.0f + erff(a * 0.70710678118654752f));
      }
    }
    __syncthreads();
    {
      const int op = tid & (S4_H - 1);
      const int sg = tid >> 7;
      const float* __restrict__ W0 = out_W + (size_t)(l * 2 * S4_H + op) * S4_H;
      const float* __restrict__ W1 = W0 + S4_H * S4_H;
      float acc0[2][S4_T], acc1[2][S4_T];
#pragma unroll
      for (int s2 = 0; s2 < 2; ++s2)
#pragma unroll
        for (int t = 0; t < S4_T; ++t) { acc0[s2][t] = 0.f; acc1[s2][t] = 0.f; }
      for (int h0 = 0; h0 < S4_H; h0 += 4) {
        const float4 w0 = *reinterpret_cast<const float4*>(W0 + h0);
        const float4 w1 = *reinterpret_cast<const float4*>(W1 + h0);
        const float w0a[4] = {w0.x, w0.y, w0.z, w0.w};
        const float w1a[4] = {w1.x, w1.y, w1.z, w1.w};
#pragma unroll
        for (int j = 0; j < 4; ++j) {
#pragma unroll
          for (int s2 = 0; s2 < 2; ++s2) {
            const float* gp = &gbuf[2 * sg + s2][h0 + j][0];
            const float4 ga = *reinterpret_cast<const float4*>(gp);
            const float4 gc = *reinterpret_cast<const float4*>(gp + 4);
            const float4 ge = *reinterpret_cast<const float4*>(gp + 8);
            const float gg[S4_T] = {ga.x, ga.y, ga.z, ga.w, gc.x, gc.y,
                                    gc.z, gc.w, ge.x, ge.y, ge.z, ge.w};
#pragma unroll
            for (int t = 0; t < S4_T; ++t) {
              acc0[s2][t] = fmaf(w0a[j], gg[t], acc0[s2][t]);
              acc1[s2][t] = fmaf(w1a[j], gg[t], acc1[s2][t]);
            }
          }
        }
      }
      const float b0 = out_b[l * 2 * S4_H + op];
      const float b1 = out_b[l * 2 * S4_H + S4_H + op];
#pragma unroll
      for (int s2 = 0; s2 < 2; ++s2) {
        const int seq = 2 * sg + s2;
#pragma unroll
        for (int t = 0; t < S4_T; ++t) {
          const float a = acc0[s2][t] + b0;
          const float g = acc1[s2][t] + b1;
          hbuf[seq][op][t] += a * (1.0f / (1.0f + expf(-g)));
        }
      }
    }
    __syncthreads();
    {
      const int col = tid >> 2;
      const int ing = tid & 3;
      if (col < S4F_SEQ * S4_T) {
        const int s = col / S4_T, t = col - s * S4_T;
        float s1 = 0.f, s2v = 0.f;
#pragma unroll
        for (int i = 0; i < S4_H / 4; ++i) {
          const float v = hbuf[s][ing * 32 + i][t];
          s1 += v;
          s2v = fmaf(v, v, s2v);
        }
        s1 += __shfl_xor(s1, 1, 4); s1 += __shfl_xor(s1, 2, 4);
        s2v += __shfl_xor(s2v, 1, 4); s2v += __shfl_xor(s2v, 2, 4);
        const float mu = s1 * (1.0f / S4_H);
        const float var = s2v * (1.0f / S4_H) - mu * mu;
        const float rstd = rsqrtf(var + 1e-5f);
#pragma unroll
        for (int i = 0; i < S4_H / 4; ++i) {
          const int h = ing * 32 + i;
          const float v = hbuf[s][h][t];
          hbuf[s][h][t] =
              fmaf((v - mu) * rstd, ln_g[l * S4_H + h], ln_b[l * S4_H + h]);
        }
      }
    }
  }
  __syncthreads();
  for (int r = tid; r < S4F_SEQ * S4_H; r += 256) {
    const int s = r >> 7, h = r & (S4_H - 1);
    const int bn = seq0 + s;
    const int b = bn >> 10, n = bn & (S4_N - 1);
    const float sw = sc_W[h], sb = sc_b[h];
#pragma unroll
    for (int q = 0; q < 3; ++q) {
      float4 o;
      const float4 hv0 = *reinterpret_cast<const float4*>(&hbuf[s][h][4 * q]);
      const float4 xv = *reinterpret_cast<const float4*>(&xbuf[s][4 * q]);
      o.x = hv0.x + fmaf(sw, xv.x, sb);
      o.y = hv0.y + fmaf(sw, xv.y, sb);
      o.z = hv0.z + fmaf(sw, xv.z, sb);
      o.w = hv0.w + fmaf(sw, xv.w, sb);
      reinterpret_cast<float4*>(out + (size_t)((b * S4_H + h) * S4_N + n) *
                                          S4_T)[q] = o;
    }
  }
}

extern "C" void kernel_launch(void* const* d_in, const int* in_sizes, int n_in,
                              void* d_out, int out_size, void* d_ws,
                              size_t ws_size, hipStream_t stream) {
  const float* x     = (const float*)d_in[0];
  const float* enc_W = (const float*)d_in[1];
  const float* enc_b = (const float*)d_in[2];
  const float* lAr   = (const float*)d_in[3];
  const float* Aim   = (const float*)d_in[4];
  const float* Cre   = (const float*)d_in[5];
  const float* Cim   = (const float*)d_in[6];
  const float* ldt   = (const float*)d_in[7];
  const float* Dp    = (const float*)d_in[8];
  const float* oW    = (const float*)d_in[9];
  const float* ob    = (const float*)d_in[10];
  const float* lg    = (const float*)d_in[11];
  const float* lb    = (const float*)d_in[12];
  const float* scW   = (const float*)d_in[13];
  const float* scb   = (const float*)d_in[14];
  float* out = (float*)d_out;

  const size_t wbytes = (size_t)(S4_NL * 2 * S4_H * S4_H) * sizeof(unsigned short); // 131072
  const size_t kbytes = (size_t)(S4_NL * S4_H * S4_T) * sizeof(float);              // 12288
  if (ws_size >= wbytes + kbytes) {
    unsigned short* Wbf = (unsigned short*)d_ws;
    float* kws = (float*)((char*)d_ws + wbytes);
    s4_prep<<<64, 256, 0, stream>>>(oW, lAr, Aim, Cre, Cim, ldt, Wbf, kws);
    s4_512<<<S4_BN / S4_SEQ, 512, 0, stream>>>(x, enc_W, enc_b, Dp, ob, lg,
                                               lb, scW, scb, Wbf, kws, out);
  } else {
    s4_main_f32<<<S4_BN / S4F_SEQ, 256, 0, stream>>>(
        x, enc_W, enc_b, lAr, Aim, Cre, Cim, ldt, Dp, oW, ob, lg, lb, scW,
        scb, out);
  }
}